// Round 9
// baseline (1952.767 us; speedup 1.0000x reference)
//
#include <hip/hip_runtime.h>

#define T_TOK 4096
#define HID   4096
#define IMD   11008

using f32x4  = __attribute__((ext_vector_type(4))) float;
using bf16x8 = __attribute__((ext_vector_type(8))) __bf16;
union FragCast { int4 i; bf16x8 b; };

__device__ __forceinline__ unsigned f2bf_bits(float f) {
  unsigned u = __float_as_uint(f);
  return (u + 0x7fffu + ((u >> 16) & 1u)) >> 16;   // RNE f32 -> bf16
}
__device__ __forceinline__ float bf2f(short s) {
  return __uint_as_float(((unsigned)(unsigned short)s) << 16);
}
__device__ __forceinline__ int4 cvt8(const float4 f0, const float4 f1) {
  int4 r;
  r.x = f2bf_bits(f0.x) | (f2bf_bits(f0.y) << 16);
  r.y = f2bf_bits(f0.z) | (f2bf_bits(f0.w) << 16);
  r.z = f2bf_bits(f1.x) | (f2bf_bits(f1.y) << 16);
  r.w = f2bf_bits(f1.z) | (f2bf_bits(f1.w) << 16);
  return r;
}
__device__ __forceinline__ void gload16(const void* g, void* l) {
  __builtin_amdgcn_global_load_lds(
      (__attribute__((address_space(1))) void*)g,
      (__attribute__((address_space(3))) void*)l, 16, 0, 0);
}

// ---------------------------------------------------------------- prep kernels
__global__ void cvt_pad(const float* __restrict__ in, short* __restrict__ out,
                        int C8, long ldin, long ldout) {
  long r = blockIdx.x;
  const float4* s = (const float4*)(in + r * ldin);
  int4* d = (int4*)(out + r * ldout);
  for (int c = threadIdx.x; c < C8; c += blockDim.x)
    d[c] = cvt8(s[2 * c], s[2 * c + 1]);
}

__global__ void build_wbT_pad(const float* __restrict__ wb,
                              short* __restrict__ out, int N, long ldout,
                              long K) {
  int n = blockIdx.x * blockDim.x + threadIdx.x;
  int ar = blockIdx.y;
  if (n < N) out[(long)n * ldout + K + ar] = (short)f2bf_bits(wb[(long)ar * N + n]);
}

__global__ void tail_copy(const short* __restrict__ src, short* dst, long ld) {
  dst[(long)blockIdx.x * ld + threadIdx.x] = src[blockIdx.x * 64 + threadIdx.x];
}

// per-token rank projection: out[t][a*16+r] = mask * sum_h Abf[t][h]*wa[a][h][r]
template <int KD, int NOUT>
__global__ __launch_bounds__(256)
void lora_proj(const short* __restrict__ Abf, long ldA,
               const float* __restrict__ wa0, const float* __restrict__ wa1,
               const int* __restrict__ seg, short* out0, long ld0, short* out1,
               long ld1) {
  __shared__ __align__(16) short rowbuf[KD];
  __shared__ float part[NOUT][4][16];
  int t = blockIdx.x, tid = threadIdx.x;
  int a = seg[t];
  const int4* src = (const int4*)(Abf + (long)t * ldA);
  for (int c = tid; c < KD / 8; c += 256) ((int4*)rowbuf)[c] = src[c];
  __syncthreads();
  int w = tid >> 6, l = tid & 63;
  int r = l & 15, g = l >> 4;
  const int HW = KD / 4;
  float s0 = 0.f, s1 = 0.f;
  const float* p0 = wa0 + (long)a * KD * 16 + r;
  const float* p1 = (NOUT == 2) ? (wa1 + (long)a * KD * 16 + r) : nullptr;
  int h = w * HW + g;
  for (int k = 0; k < HW / 4; ++k, h += 4) {
    float xv = bf2f(rowbuf[h]);
    s0 = fmaf(xv, p0[(long)h * 16], s0);
    if (NOUT == 2) s1 = fmaf(xv, p1[(long)h * 16], s1);
  }
  s0 += __shfl_xor(s0, 16); s0 += __shfl_xor(s0, 32);
  if (NOUT == 2) { s1 += __shfl_xor(s1, 16); s1 += __shfl_xor(s1, 32); }
  if (l < 16) { part[0][w][r] = s0; if (NOUT == 2) part[1][w][r] = s1; }
  __syncthreads();
  if (tid < 64 * NOUT) {
    int m = tid >> 6, ar = tid & 63;
    float v = 0.f;
    if ((ar >> 4) == a) {
      int r2 = ar & 15;
      v = part[m][0][r2] + part[m][1][r2] + part[m][2][r2] + part[m][3][r2];
    }
    short b = (short)f2bf_bits(v);
    if (m == 0) out0[(long)t * ld0 + ar] = b;
    else        out1[(long)t * ld1 + ar] = b;
  }
}

// --------------------- GEMM A: exact m97 replica (multi-block TLP regime)
// 128x128 tile, BK=32, 256 thr = 4 waves (2x2, 64x64 each). Single-buffered
// LDS 16KB (A 8K + B 8K, LINEAR [128][32] bf16, 64B rows, no swizzle).
// Per K-step: __syncthreads (WAR) -> 4x global_load_lds dwordx4 ->
// __syncthreads (vmcnt(0)) -> 8x ds_read_b128 -> 16 MFMA. No asm/setprio:
// rely on multi-block co-residency for latency hiding (m114).
// R8 BUGFIX: fragment offsets were computed for 128B rows; correct 64B-row
// offsets are w*4096 + lrow*64 + lhi*16, fragment stride mi*1024.
template <int MODE>  // 0: bf16 store; 1: silu(gbuf)*acc -> bf16; 2: f32
__global__ __launch_bounds__(256)
void gemm97(const short* __restrict__ A, const short* __restrict__ B,
            const short* __restrict__ gbuf, short* __restrict__ outB,
            float* __restrict__ outF, int nbx, long ldK, int iters, long ldo) {
  __shared__ __align__(16) short sA[128 * 32];
  __shared__ __align__(16) short sB[128 * 32];

  int nwg = gridDim.x;
  int orig = blockIdx.x;
  int q = nwg >> 3, rr = nwg & 7;
  int xcd = orig & 7, loc = orig >> 3;
  int swz = (xcd < rr ? xcd * (q + 1) : rr * (q + 1) + (xcd - rr) * q) + loc;
  int bx = swz % nbx, by = swz / nbx;   // row fastest: B panel reused in L2
  long row0 = (long)bx * 128, col0 = (long)by * 128;

  int tid = threadIdx.x;
  int l = tid & 63, wid = tid >> 6;
  int wr = wid >> 1, wc = wid & 1;      // 2x2 waves, 64x64 each
  int lrow = l & 15, lhi = l >> 4;

  // staging: 512 x 16B chunks per tile; thread t -> chunks t, t+256
  // (chunk c = row (c>>2), k-slice (c&3)*8 elems; LDS linear c*16).
  int r0 = tid >> 2, k0 = (tid & 3) * 8;
  const short* aS0 = A + (row0 + r0) * ldK + k0;
  const short* aS1 = A + (row0 + r0 + 64) * ldK + k0;
  const short* bS0 = B + (col0 + r0) * ldK + k0;
  const short* bS1 = B + (col0 + r0 + 64) * ldK + k0;
  char* dA0 = (char*)sA + tid * 16; char* dA1 = dA0 + 4096;
  char* dB0 = (char*)sB + tid * 16; char* dB1 = dB0 + 4096;

  f32x4 acc[4][4];
  f32x4 zr = {0.f, 0.f, 0.f, 0.f};
#pragma unroll
  for (int mi = 0; mi < 4; ++mi)
#pragma unroll
    for (int ni = 0; ni < 4; ++ni) acc[mi][ni] = zr;

  const int aOff = wr * 4096 + lrow * 64 + lhi * 16;  // bytes into sA (64B rows)
  const int bOff = wc * 4096 + lrow * 64 + lhi * 16;

#pragma unroll 1
  for (int it = 0; it < iters; ++it) {
    __syncthreads();                         // prev readers done (WAR)
    gload16(aS0, dA0); gload16(aS1, dA1);
    gload16(bS0, dB0); gload16(bS1, dB1);
    aS0 += 32; aS1 += 32; bS0 += 32; bS1 += 32;
    __syncthreads();                         // vmcnt(0): tile landed
    bf16x8 aF[4], bF[4];
#pragma unroll
    for (int mi = 0; mi < 4; ++mi) {
      FragCast f; f.i = *(const int4*)((const char*)sA + aOff + mi * 1024);
      aF[mi] = f.b;
    }
#pragma unroll
    for (int ni = 0; ni < 4; ++ni) {
      FragCast f; f.i = *(const int4*)((const char*)sB + bOff + ni * 1024);
      bF[ni] = f.b;
    }
#pragma unroll
    for (int mi = 0; mi < 4; ++mi)
#pragma unroll
      for (int ni = 0; ni < 4; ++ni)
        acc[mi][ni] = __builtin_amdgcn_mfma_f32_16x16x32_bf16(
            aF[mi], bF[ni], acc[mi][ni], 0, 0, 0);
  }

  // epilogue: C/D layout col=lane&15, row=(lane>>4)*4+reg  [m89]
#pragma unroll
  for (int mi = 0; mi < 4; ++mi)
#pragma unroll
    for (int ni = 0; ni < 4; ++ni)
#pragma unroll
      for (int j = 0; j < 4; ++j) {
        long grow = row0 + wr * 64 + mi * 16 + lhi * 4 + j;
        long gcol = col0 + wc * 64 + ni * 16 + lrow;
        long idx = grow * ldo + gcol;
        float v = acc[mi][ni][j];
        if constexpr (MODE == 0) {
          outB[idx] = (short)f2bf_bits(v);
        } else if constexpr (MODE == 1) {
          float g = bf2f(gbuf[idx]);
          float t2 = g * (1.f / (1.f + __expf(-g))) * v;
          outB[idx] = (short)f2bf_bits(t2);
        } else {
          outF[idx] = v;
        }
      }
}

// --------------------- GEMM B: R5 control (best measured, 570us) — verbatim
template <int MODE>
__global__ __launch_bounds__(512, 2)
void gemm256(const short* __restrict__ A, const short* __restrict__ B,
             const short* gbuf, short* outB, float* outF, int nby, long ldK,
             int iters, long ldo) {
  extern __shared__ __align__(16) char smem[];

  int nwg = gridDim.x;
  int orig = blockIdx.x;
  int q = nwg >> 3, rr = nwg & 7;
  int xcd = orig & 7, loc = orig >> 3;
  int swz = (xcd < rr ? xcd * (q + 1) : rr * (q + 1) + (xcd - rr) * q) + loc;
  int by = swz % nby, bx = swz / nby;
  long row0 = (long)bx * 256, col0 = (long)by * 256;

  int tid = threadIdx.x;
  int l = tid & 63, wid = tid >> 6;
  int wr = wid >> 2, wc = wid & 3;
  int lrow = l & 15, lhi = l >> 4, md = lrow & 7;

  const short* aP[4]; const short* bP[4];
  int dst[4];
#pragma unroll
  for (int k = 0; k < 4; ++k) {
    int idx = tid + k * 512;
    int r = idx >> 3, c8 = idx & 7;
    aP[k] = A + (row0 + r) * ldK + (c8 ^ (r & 7)) * 8;
    bP[k] = B + (col0 + r) * ldK + (c8 ^ (r & 7)) * 8;
    dst[k] = idx * 16;
  }

  auto stageA = [&](int bi) {
    char* d = smem + bi * 32768;
#pragma unroll
    for (int k = 0; k < 4; ++k) { gload16(aP[k], d + dst[k]); aP[k] += 64; }
  };
  auto stageB = [&](int bi) {
    char* d = smem + 98304 + bi * 32768;
#pragma unroll
    for (int k = 0; k < 4; ++k) { gload16(bP[k], d + dst[k]); bP[k] += 64; }
  };

  f32x4 acc[8][4];
  f32x4 zr = {0.f, 0.f, 0.f, 0.f};
#pragma unroll
  for (int mi = 0; mi < 8; ++mi)
#pragma unroll
    for (int ni = 0; ni < 4; ++ni) acc[mi][ni] = zr;

  const int csel0 = (lhi ^ md) * 16;
  const int csel1 = ((4 + lhi) ^ md) * 16;

  stageA(0); stageB(0); stageA(1);
  int ca = 0, sa = 2;
  for (int t = 0; t < iters; ++t) {
    if (t + 1 < iters) asm volatile("s_waitcnt vmcnt(4)" ::: "memory");
    else               asm volatile("s_waitcnt vmcnt(0)" ::: "memory");
    asm volatile("s_barrier" ::: "memory");
    if (t + 1 < iters) stageB((t + 1) & 1);
    if (t + 2 < iters) { stageA(sa); sa = (sa == 2) ? 0 : sa + 1; }

    const char* Ab = smem + ca * 32768;
    const char* Bb = smem + 98304 + (t & 1) * 32768;
    ca = (ca == 2) ? 0 : ca + 1;

    bf16x8 bF[4][2];
#pragma unroll
    for (int ni = 0; ni < 4; ++ni) {
      const char* base = Bb + (wc * 64 + ni * 16 + lrow) * 128;
      FragCast f0, f1;
      f0.i = *(const int4*)(base + csel0);
      f1.i = *(const int4*)(base + csel1);
      bF[ni][0] = f0.b; bF[ni][1] = f1.b;
    }
#pragma unroll
    for (int qm = 0; qm < 2; ++qm) {
      bf16x8 aF[4][2];
#pragma unroll
      for (int mi = 0; mi < 4; ++mi) {
        const char* base = Ab + (wr * 128 + qm * 64 + mi * 16 + lrow) * 128;
        FragCast f0, f1;
        f0.i = *(const int4*)(base + csel0);
        f1.i = *(const int4*)(base + csel1);
        aF[mi][0] = f0.b; aF[mi][1] = f1.b;
      }
      __builtin_amdgcn_s_setprio(1);
#pragma unroll
      for (int mi = 0; mi < 4; ++mi)
#pragma unroll
        for (int ni = 0; ni < 4; ++ni) {
          acc[qm * 4 + mi][ni] = __builtin_amdgcn_mfma_f32_16x16x32_bf16(
              aF[mi][0], bF[ni][0], acc[qm * 4 + mi][ni], 0, 0, 0);
          acc[qm * 4 + mi][ni] = __builtin_amdgcn_mfma_f32_16x16x32_bf16(
              aF[mi][1], bF[ni][1], acc[qm * 4 + mi][ni], 0, 0, 0);
        }
      __builtin_amdgcn_s_setprio(0);
    }
  }

#pragma unroll
  for (int qm = 0; qm < 2; ++qm)
#pragma unroll
    for (int mi = 0; mi < 4; ++mi)
#pragma unroll
      for (int ni = 0; ni < 4; ++ni)
#pragma unroll
        for (int j = 0; j < 4; ++j) {
          long grow = row0 + wr * 128 + qm * 64 + mi * 16 + lhi * 4 + j;
          long gcol = col0 + wc * 64 + ni * 16 + lrow;
          long idx = grow * ldo + gcol;
          float v = acc[qm * 4 + mi][ni][j];
          if constexpr (MODE == 0) {
            outB[idx] = (short)f2bf_bits(v);
          } else if constexpr (MODE == 1) {
            float g = bf2f(gbuf[idx]);
            float t2 = g * (1.f / (1.f + __expf(-g))) * v;
            outB[idx] = (short)f2bf_bits(t2);
          } else {
            outF[idx] = v;
          }
        }
}

// ---------------------------------------------------------------- launcher
extern "C" void kernel_launch(void* const* d_in, const int* in_sizes, int n_in,
                              void* d_out, int out_size, void* d_ws,
                              size_t ws_size, hipStream_t stream) {
  const float* x       = (const float*)d_in[0];
  const float* gate_w  = (const float*)d_in[1];
  const float* up_w    = (const float*)d_in[2];
  const float* down_w  = (const float*)d_in[3];
  const float* gate_wa = (const float*)d_in[4];
  const float* gate_wb = (const float*)d_in[5];
  const float* up_wa   = (const float*)d_in[6];
  const float* up_wb   = (const float*)d_in[7];
  const float* down_wa = (const float*)d_in[8];
  const float* down_wb = (const float*)d_in[9];
  const int*   seg     = (const int*)d_in[10];

  char* ws = (char*)d_ws;
  short* xg_pad = (short*)(ws);                   // [4096][4160]  34.1 MB
  short* wA     = (short*)(ws + 34078720);        // gate_w pad -> down_w pad
  short* wB     = (short*)(ws + 125665280);       // up_w pad      91.6 MB
  short* t_pad  = (short*)(ws + 217251840);       // [4096][11072] 90.7 MB
  short* xa_u   = (short*)(ws + 307953664);       // [4096][64]

  const int LDS_BYTES = 163840;
  hipFuncSetAttribute(reinterpret_cast<const void*>(&gemm256<1>),
                      hipFuncAttributeMaxDynamicSharedMemorySize, LDS_BYTES);

  // bf16 padded operand build
  cvt_pad<<<T_TOK, 256, 0, stream>>>(x, xg_pad, 512, HID, 4160);
  cvt_pad<<<IMD, 256, 0, stream>>>(gate_w, wA, 512, HID, 4160);
  cvt_pad<<<IMD, 256, 0, stream>>>(up_w, wB, 512, HID, 4160);
  build_wbT_pad<<<dim3(43, 64), 256, 0, stream>>>(gate_wb, wA, IMD, 4160, HID);
  build_wbT_pad<<<dim3(43, 64), 256, 0, stream>>>(up_wb, wB, IMD, 4160, HID);
  lora_proj<HID, 2><<<T_TOK, 256, 0, stream>>>(
      xg_pad, 4160, gate_wa, up_wa, seg, xg_pad + HID, 4160, xa_u, 64);

  // gate (A-arm: m97 replica): t_pad = x @ gate_w^T + lora  [K'=4160, 130 steps]
  gemm97<0><<<32 * 86, 256, 0, stream>>>(
      xg_pad, wA, nullptr, t_pad, nullptr, 32, 4160, 130, 11072);

  // up (B-arm: R5 control): t_pad = silu(t_pad) * (x @ up_w^T + lora)
  tail_copy<<<T_TOK, 64, 0, stream>>>(xa_u, xg_pad + HID, 4160);
  gemm256<1><<<16 * 43, 512, LDS_BYTES, stream>>>(
      xg_pad, wB, t_pad, t_pad, nullptr, 43, 4160, 65, 11072);

  // down operand build (wA free after gate GEMM)
  cvt_pad<<<T_TOK, 256, 0, stream>>>(down_w, wA, 1376, IMD, 11072);
  build_wbT_pad<<<dim3(16, 64), 256, 0, stream>>>(down_wb, wA, HID, 11072, IMD);
  lora_proj<IMD, 1><<<T_TOK, 256, 0, stream>>>(
      t_pad, 11072, down_wa, nullptr, seg, t_pad + IMD, 11072, nullptr, 64);

  // down (m97 replica): out = t @ down_w^T + lora  [K'=11072, 346 steps]
  gemm97<2><<<32 * 32, 256, 0, stream>>>(
      t_pad, wA, nullptr, nullptr, (float*)d_out, 32, 11072, 346, 4096);
}

// Round 10
// 1704.409 us; speedup vs baseline: 1.1457x; 1.1457x over previous
//
#include <hip/hip_runtime.h>

#define T_TOK 4096
#define HID   4096
#define IMD   11008

using f32x4  = __attribute__((ext_vector_type(4))) float;
using bf16x8 = __attribute__((ext_vector_type(8))) __bf16;
union FragCast { int4 i; bf16x8 b; };

__device__ __forceinline__ unsigned f2bf_bits(float f) {
  unsigned u = __float_as_uint(f);
  return (u + 0x7fffu + ((u >> 16) & 1u)) >> 16;   // RNE f32 -> bf16
}
__device__ __forceinline__ float bf2f(short s) {
  return __uint_as_float(((unsigned)(unsigned short)s) << 16);
}
__device__ __forceinline__ int4 cvt8(const float4 f0, const float4 f1) {
  int4 r;
  r.x = f2bf_bits(f0.x) | (f2bf_bits(f0.y) << 16);
  r.y = f2bf_bits(f0.z) | (f2bf_bits(f0.w) << 16);
  r.z = f2bf_bits(f1.x) | (f2bf_bits(f1.y) << 16);
  r.w = f2bf_bits(f1.z) | (f2bf_bits(f1.w) << 16);
  return r;
}
__device__ __forceinline__ void gload16(const void* g, void* l) {
  __builtin_amdgcn_global_load_lds(
      (__attribute__((address_space(1))) void*)g,
      (__attribute__((address_space(3))) void*)l, 16, 0, 0);
}

// ---------------------------------------------------------------- prep kernels
__global__ void cvt_pad(const float* __restrict__ in, short* __restrict__ out,
                        int C8, long ldin, long ldout) {
  long r = blockIdx.x;
  const float4* s = (const float4*)(in + r * ldin);
  int4* d = (int4*)(out + r * ldout);
  for (int c = threadIdx.x; c < C8; c += blockDim.x)
    d[c] = cvt8(s[2 * c], s[2 * c + 1]);
}

__global__ void build_wbT_pad(const float* __restrict__ wb,
                              short* __restrict__ out, int N, long ldout,
                              long K) {
  int n = blockIdx.x * blockDim.x + threadIdx.x;
  int ar = blockIdx.y;
  if (n < N) out[(long)n * ldout + K + ar] = (short)f2bf_bits(wb[(long)ar * N + n]);
}

__global__ void tail_copy(const short* __restrict__ src, short* dst, long ld) {
  dst[(long)blockIdx.x * ld + threadIdx.x] = src[blockIdx.x * 64 + threadIdx.x];
}

// per-token rank projection: out[t][a*16+r] = mask * sum_h Abf[t][h]*wa[a][h][r]
template <int KD, int NOUT>
__global__ __launch_bounds__(256)
void lora_proj(const short* __restrict__ Abf, long ldA,
               const float* __restrict__ wa0, const float* __restrict__ wa1,
               const int* __restrict__ seg, short* out0, long ld0, short* out1,
               long ld1) {
  __shared__ __align__(16) short rowbuf[KD];
  __shared__ float part[NOUT][4][16];
  int t = blockIdx.x, tid = threadIdx.x;
  int a = seg[t];
  const int4* src = (const int4*)(Abf + (long)t * ldA);
  for (int c = tid; c < KD / 8; c += 256) ((int4*)rowbuf)[c] = src[c];
  __syncthreads();
  int w = tid >> 6, l = tid & 63;
  int r = l & 15, g = l >> 4;
  const int HW = KD / 4;
  float s0 = 0.f, s1 = 0.f;
  const float* p0 = wa0 + (long)a * KD * 16 + r;
  const float* p1 = (NOUT == 2) ? (wa1 + (long)a * KD * 16 + r) : nullptr;
  int h = w * HW + g;
  for (int k = 0; k < HW / 4; ++k, h += 4) {
    float xv = bf2f(rowbuf[h]);
    s0 = fmaf(xv, p0[(long)h * 16], s0);
    if (NOUT == 2) s1 = fmaf(xv, p1[(long)h * 16], s1);
  }
  s0 += __shfl_xor(s0, 16); s0 += __shfl_xor(s0, 32);
  if (NOUT == 2) { s1 += __shfl_xor(s1, 16); s1 += __shfl_xor(s1, 32); }
  if (l < 16) { part[0][w][r] = s0; if (NOUT == 2) part[1][w][r] = s1; }
  __syncthreads();
  if (tid < 64 * NOUT) {
    int m = tid >> 6, ar = tid & 63;
    float v = 0.f;
    if ((ar >> 4) == a) {
      int r2 = ar & 15;
      v = part[m][0][r2] + part[m][1][r2] + part[m][2][r2] + part[m][3][r2];
    }
    short b = (short)f2bf_bits(v);
    if (m == 0) out0[(long)t * ld0 + ar] = b;
    else        out1[(long)t * ld1 + ar] = b;
  }
}

// ------------------------------------- GEMM: 256x256, 4-phase/K-step pipeline
// (round-5 kernel, measured gate/up=570us down~312us, verbatim except ORDER)
// ORDER=0: col-fastest within XCD chunk (by=swz%nby) — down (B panel 5.6MB
//   exceeds L2; both operands L3-resident anyway).
// ORDER=1: bx-fastest (bx=swz&15, by=swz>>4; requires nbx==16) — gate/up:
//   the 16 row-blocks sharing a 2.13MB B col-panel become consecutive blocks
//   on ONE XCD, co-resident on its 32 CUs -> B staged from XCD L2; A (34MB)
//   L3-resident. Targets the staging-supply limit (R9 analysis).
template <int MODE, int ORDER>  // MODE 0: bf16; 1: silu(gbuf)*acc bf16; 2: f32
__global__ __launch_bounds__(512, 2)
void gemm256(const short* __restrict__ A, const short* __restrict__ B,
             const short* gbuf, short* outB, float* outF, int nby, long ldK,
             int iters, long ldo) {
  extern __shared__ __align__(16) char smem[];
  // A bufs: 3 x 32KB at 0; B bufs: 2 x 32KB at 98304.

  int nwg = gridDim.x;
  int orig = blockIdx.x;
  int q = nwg >> 3, rr = nwg & 7;
  int xcd = orig & 7, loc = orig >> 3;
  int swz = (xcd < rr ? xcd * (q + 1) : rr * (q + 1) + (xcd - rr) * q) + loc;
  int by, bx;
  if constexpr (ORDER == 0) { by = swz % nby; bx = swz / nby; }
  else                      { bx = swz & 15;  by = swz >> 4;  }
  long row0 = (long)bx * 256, col0 = (long)by * 256;

  int tid = threadIdx.x;
  int l = tid & 63, wid = tid >> 6;
  int wr = wid >> 2, wc = wid & 3;      // 2M x 4N waves, 128x64 each
  int lrow = l & 15, lhi = l >> 4, md = lrow & 7;

  const short* aP[4]; const short* bP[4];
  int dst[4];
#pragma unroll
  for (int k = 0; k < 4; ++k) {
    int idx = tid + k * 512;
    int r = idx >> 3, c8 = idx & 7;
    aP[k] = A + (row0 + r) * ldK + (c8 ^ (r & 7)) * 8;
    bP[k] = B + (col0 + r) * ldK + (c8 ^ (r & 7)) * 8;
    dst[k] = idx * 16;
  }

  // stage one half-tile (h=0: rows 0-127, h=1: rows 128-255) = 2 gloads
  auto stageA_h = [&](int bi, int h) {
    char* d = smem + bi * 32768;
    gload16(aP[2 * h], d + dst[2 * h]);         aP[2 * h] += 64;
    gload16(aP[2 * h + 1], d + dst[2 * h + 1]); aP[2 * h + 1] += 64;
  };
  auto stageB_h = [&](int bi, int h) {
    char* d = smem + 98304 + bi * 32768;
    gload16(bP[2 * h], d + dst[2 * h]);         bP[2 * h] += 64;
    gload16(bP[2 * h + 1], d + dst[2 * h + 1]); bP[2 * h + 1] += 64;
  };

  f32x4 acc[8][4];
  f32x4 zr = {0.f, 0.f, 0.f, 0.f};
#pragma unroll
  for (int mi = 0; mi < 8; ++mi)
#pragma unroll
    for (int ni = 0; ni < 4; ++ni) acc[mi][ni] = zr;

  const int csel0 = (lhi ^ md) * 16;
  const int csel1 = ((4 + lhi) ^ md) * 16;

  // prologue: A(0), B(0), A(1); confirm A(0),B(0); keep A(1) in flight
  stageA_h(0, 0); stageA_h(0, 1);
  stageB_h(0, 0); stageB_h(0, 1);
  stageA_h(1, 0); stageA_h(1, 1);
  asm volatile("s_waitcnt vmcnt(4)" ::: "memory");
  asm volatile("s_barrier" ::: "memory");

  int ca = 0;                             // A buffer holding A(t)
#pragma unroll 1
  for (int t = 0; t < iters; ++t) {
    const char* Ab = smem + ca * 32768;
    const char* Bb = smem + 98304 + (t & 1) * 32768;
    int na2 = (ca >= 1) ? ca - 1 : 2;     // (ca+2)%3 : buffer for A(t+2)
    int nb1 = (t + 1) & 1;
    bf16x8 bF[4][2];

#pragma unroll
    for (int p = 0; p < 4; ++p) {
      // --- ds_read register subtile for this phase
      if (p == 0) {
#pragma unroll
        for (int ni = 0; ni < 4; ++ni) {
          const char* base = Bb + (wc * 64 + ni * 16 + lrow) * 128;
          FragCast f0, f1;
          f0.i = *(const int4*)(base + csel0);
          f1.i = *(const int4*)(base + csel1);
          bF[ni][0] = f0.b; bF[ni][1] = f1.b;
        }
      }
      bf16x8 aF[2][2];
#pragma unroll
      for (int m2 = 0; m2 < 2; ++m2) {
        const char* base = Ab + (wr * 128 + p * 32 + m2 * 16 + lrow) * 128;
        FragCast f0, f1;
        f0.i = *(const int4*)(base + csel0);
        f1.i = *(const int4*)(base + csel1);
        aF[m2][0] = f0.b; aF[m2][1] = f1.b;
      }
      // --- stage one half-tile
      if (p == 0 && t + 1 < iters) stageB_h(nb1, 0);
      if (p == 1 && t + 1 < iters) stageB_h(nb1, 1);
      if (p == 2 && t + 2 < iters) stageA_h(na2, 0);
      if (p == 3) {
        if (t + 2 < iters) {
          stageA_h(na2, 1);
          asm volatile("s_waitcnt vmcnt(4)" ::: "memory");
        } else {
          asm volatile("s_waitcnt vmcnt(0)" ::: "memory");
        }
      }
      asm volatile("s_barrier" ::: "memory");
      // --- MFMA cluster (k-outer: 8 independent accs between reuse)
      __builtin_amdgcn_s_setprio(1);
#pragma unroll
      for (int k = 0; k < 2; ++k)
#pragma unroll
        for (int m2 = 0; m2 < 2; ++m2)
#pragma unroll
          for (int ni = 0; ni < 4; ++ni)
            acc[p * 2 + m2][ni] = __builtin_amdgcn_mfma_f32_16x16x32_bf16(
                aF[m2][k], bF[ni][k], acc[p * 2 + m2][ni], 0, 0, 0);
      __builtin_amdgcn_s_setprio(0);
      asm volatile("s_barrier" ::: "memory");
    }
    ca = (ca == 2) ? 0 : ca + 1;
  }

  // epilogue: C/D layout col=lane&15, row=(lane>>4)*4+reg  [m89]
#pragma unroll
  for (int mi = 0; mi < 8; ++mi)
#pragma unroll
    for (int ni = 0; ni < 4; ++ni)
#pragma unroll
      for (int j = 0; j < 4; ++j) {
        long grow = row0 + wr * 128 + mi * 16 + lhi * 4 + j;
        long gcol = col0 + wc * 64 + ni * 16 + lrow;
        long idx = grow * ldo + gcol;
        float v = acc[mi][ni][j];
        if constexpr (MODE == 0) {
          outB[idx] = (short)f2bf_bits(v);
        } else if constexpr (MODE == 1) {
          float g = bf2f(gbuf[idx]);
          float t2 = g * (1.f / (1.f + __expf(-g))) * v;   // silu(g)*u
          outB[idx] = (short)f2bf_bits(t2);
        } else {
          outF[idx] = v;
        }
      }
}

// ---------------------------------------------------------------- launcher
extern "C" void kernel_launch(void* const* d_in, const int* in_sizes, int n_in,
                              void* d_out, int out_size, void* d_ws,
                              size_t ws_size, hipStream_t stream) {
  const float* x       = (const float*)d_in[0];
  const float* gate_w  = (const float*)d_in[1];
  const float* up_w    = (const float*)d_in[2];
  const float* down_w  = (const float*)d_in[3];
  const float* gate_wa = (const float*)d_in[4];
  const float* gate_wb = (const float*)d_in[5];
  const float* up_wa   = (const float*)d_in[6];
  const float* up_wb   = (const float*)d_in[7];
  const float* down_wa = (const float*)d_in[8];
  const float* down_wb = (const float*)d_in[9];
  const int*   seg     = (const int*)d_in[10];

  char* ws = (char*)d_ws;
  short* xg_pad = (short*)(ws);                   // [4096][4160]  34.1 MB
  short* wA     = (short*)(ws + 34078720);        // gate_w pad -> down_w pad
  short* wB     = (short*)(ws + 125665280);       // up_w pad      91.6 MB
  short* t_pad  = (short*)(ws + 217251840);       // [4096][11072] 90.7 MB
  short* xa_u   = (short*)(ws + 307953664);       // [4096][64]

  const int LDS_BYTES = 163840;   // 3 x 32KB A + 2 x 32KB B
  hipFuncSetAttribute(reinterpret_cast<const void*>(&gemm256<0, 1>),
                      hipFuncAttributeMaxDynamicSharedMemorySize, LDS_BYTES);
  hipFuncSetAttribute(reinterpret_cast<const void*>(&gemm256<1, 1>),
                      hipFuncAttributeMaxDynamicSharedMemorySize, LDS_BYTES);
  hipFuncSetAttribute(reinterpret_cast<const void*>(&gemm256<2, 0>),
                      hipFuncAttributeMaxDynamicSharedMemorySize, LDS_BYTES);

  // bf16 padded operand build
  cvt_pad<<<T_TOK, 256, 0, stream>>>(x, xg_pad, 512, HID, 4160);
  cvt_pad<<<IMD, 256, 0, stream>>>(gate_w, wA, 512, HID, 4160);
  cvt_pad<<<IMD, 256, 0, stream>>>(up_w, wB, 512, HID, 4160);
  build_wbT_pad<<<dim3(43, 64), 256, 0, stream>>>(gate_wb, wA, IMD, 4160, HID);
  build_wbT_pad<<<dim3(43, 64), 256, 0, stream>>>(up_wb, wB, IMD, 4160, HID);
  lora_proj<HID, 2><<<T_TOK, 256, 0, stream>>>(
      xg_pad, 4160, gate_wa, up_wa, seg, xg_pad + HID, 4160, xa_u, 64);

  // gate: t_pad = x @ gate_w^T + lora   [M=4096, N=11008, K'=4160] bx-fastest
  gemm256<0, 1><<<16 * 43, 512, LDS_BYTES, stream>>>(
      xg_pad, wA, nullptr, t_pad, nullptr, 43, 4160, 65, 11072);
  // swap LoRA tail to up's xa, then up+silu fuse (in place over t_pad)
  tail_copy<<<T_TOK, 64, 0, stream>>>(xa_u, xg_pad + HID, 4160);
  gemm256<1, 1><<<16 * 43, 512, LDS_BYTES, stream>>>(
      xg_pad, wB, t_pad, t_pad, nullptr, 43, 4160, 65, 11072);

  // down operand build (wA region is free after gate GEMM)
  cvt_pad<<<T_TOK, 256, 0, stream>>>(down_w, wA, 1376, IMD, 11072);
  build_wbT_pad<<<dim3(16, 64), 256, 0, stream>>>(down_wb, wA, HID, 11072, IMD);
  lora_proj<IMD, 1><<<T_TOK, 256, 0, stream>>>(
      t_pad, 11072, down_wa, nullptr, seg, t_pad + IMD, 11072, nullptr, 64);

  // down: out = t @ down_w^T + lora     [M=4096, N=4096, K'=11072] col-fastest
  gemm256<2, 0><<<16 * 16, 512, LDS_BYTES, stream>>>(
      t_pad, wA, nullptr, nullptr, (float*)d_out, 16, 11072, 173, 4096);
}